// Round 1
// baseline (704.070 us; speedup 1.0000x reference)
//
#include <hip/hip_runtime.h>
#include <stdint.h>
#include <stddef.h>

// GraphConvolution: out = relu(S @ S @ S @ ((x .* mask / 0.9) @ W))
//   x: [16384,512] f32, S: [16384,16384] f32, W: [512,128] f32, mask: [16384,512] f32
// Strategy: bf16 MFMA (16x16x32), S converted fp32->bf16 in registers (stream once
// per pass, 3.22 GB total => ~512us HBM floor). Feat kept transposed bf16 [128][16384].
// K-split=4 with fp32 partials in ws + reduce kernels (deterministic, no atomics).

#define NROWS 16384
#define KDIN  512
#define NDOUT 128

typedef __attribute__((ext_vector_type(8))) short bf16x8;
typedef __attribute__((ext_vector_type(4))) float f32x4;

__device__ __forceinline__ unsigned short f2bf(float f) {
  union { float f; unsigned u; } v; v.f = f;
  unsigned r = v.u + 0x7FFFu + ((v.u >> 16) & 1u);   // RNE
  return (unsigned short)(r >> 16);
}

__device__ __forceinline__ void gld_lds16(const void* g, void* l) {
  __builtin_amdgcn_global_load_lds(
      (const __attribute__((address_space(1))) void*)g,
      (__attribute__((address_space(3))) void*)l, 16, 0, 0);
}

__device__ __forceinline__ float4 dmul(float4 a, float4 m) {
  const float s = (float)(1.0 / 0.9);
  float4 r; r.x = a.x*m.x*s; r.y = a.y*m.y*s; r.z = a.z*m.z*s; r.w = a.w*m.w*s;
  return r;
}

// C = A[ M x K, f32 (optionally * mask * 1/0.9) ] @ B  where B given transposed
// bf16 BT[128][ldb]. Writes fp32 partials part[KSPL][NROWS][128].
// Block: 512 threads = 8 waves, each wave 16 rows; tile BM=128 x N=128.
template<int DROP, int KSPL>
__global__ __launch_bounds__(512, 4)
void gemm_stage(const float* __restrict__ A, const float* __restrict__ Am,
                const unsigned short* __restrict__ BT,
                int lda, int ldb, int kchunk,
                float* __restrict__ part)
{
  __shared__ unsigned short ldsB[2 * 8192];   // 2 x [128 n][64 k] bf16 = 32 KiB
  const int tid = threadIdx.x;
  const int w = tid >> 6, l = tid & 63;
  const int g = l >> 4, lm = l & 15;
  const int bx = blockIdx.x;
  const int mtile = bx / KSPL, ks = bx % KSPL;
  const int k0 = ks * kchunk;
  const int nst = kchunk >> 6;               // stages of BK=64

  // A: each lane owns row (w*16 + lm), k-offset g*8 within each 32-k chunk
  const int arow = mtile * 128 + w * 16 + lm;
  const float* ap = A + (size_t)arow * lda + k0 + g * 8;
  const float* mp = DROP ? (Am + (size_t)arow * lda + k0 + g * 8) : (const float*)0;

  // B staging: thread -> (n, 16B-chunk c); source pre-swizzled so LDS stays linear,
  // read side applies the same XOR => bank-conflict-free ds_read_b128.
  const int n0 = tid >> 3, c = tid & 7;
  const int n1 = n0 + 64;
  const unsigned short* bs0 = BT + (size_t)n0 * ldb + k0 + ((c ^ (n0 & 7)) << 3);
  const unsigned short* bs1 = BT + (size_t)n1 * ldb + k0 + ((c ^ (n1 & 7)) << 3);

  f32x4 acc[8];
  #pragma unroll
  for (int i = 0; i < 8; ++i) acc[i] = (f32x4){0.f, 0.f, 0.f, 0.f};

  float4 cur0, cur1, cur2, cur3, nxt0, nxt1, nxt2, nxt3;

  // prologue: stage 0
  {
    unsigned short* d0 = ldsB + tid * 8;
    gld_lds16(bs0, d0);
    gld_lds16(bs1, d0 + 4096);
    cur0 = *(const float4*)(ap);
    cur1 = *(const float4*)(ap + 4);
    cur2 = *(const float4*)(ap + 32);
    cur3 = *(const float4*)(ap + 36);
    if (DROP) {
      cur0 = dmul(cur0, *(const float4*)(mp));
      cur1 = dmul(cur1, *(const float4*)(mp + 4));
      cur2 = dmul(cur2, *(const float4*)(mp + 32));
      cur3 = dmul(cur3, *(const float4*)(mp + 36));
    }
  }

  for (int t = 0; t < nst; ++t) {
    const int buf = t & 1;
    if (t + 1 < nst) {
      unsigned short* d0 = ldsB + ((t + 1) & 1) * 8192 + tid * 8;
      gld_lds16(bs0 + (size_t)(t + 1) * 64, d0);
      gld_lds16(bs1 + (size_t)(t + 1) * 64, d0 + 4096);
      const float* p = ap + (size_t)(t + 1) * 64;
      nxt0 = *(const float4*)(p);
      nxt1 = *(const float4*)(p + 4);
      nxt2 = *(const float4*)(p + 32);
      nxt3 = *(const float4*)(p + 36);
      if (DROP) {
        const float* q = mp + (size_t)(t + 1) * 64;
        nxt0 = dmul(nxt0, *(const float4*)(q));
        nxt1 = dmul(nxt1, *(const float4*)(q + 4));
        nxt2 = dmul(nxt2, *(const float4*)(q + 32));
        nxt3 = dmul(nxt3, *(const float4*)(q + 36));
      }
    }
    __syncthreads();
    const char* lb = (const char*)ldsB + buf * 16384;
    #pragma unroll
    for (int kk = 0; kk < 2; ++kk) {
      const float4 u = kk ? cur2 : cur0;
      const float4 v = kk ? cur3 : cur1;
      bf16x8 af;
      af[0] = (short)f2bf(u.x); af[1] = (short)f2bf(u.y);
      af[2] = (short)f2bf(u.z); af[3] = (short)f2bf(u.w);
      af[4] = (short)f2bf(v.x); af[5] = (short)f2bf(v.y);
      af[6] = (short)f2bf(v.z); af[7] = (short)f2bf(v.w);
      #pragma unroll
      for (int nt = 0; nt < 8; ++nt) {
        const int n = nt * 16 + lm;
        const int off = n * 128 + (((kk << 6) + (g << 4)) ^ ((n & 7) << 4));
        bf16x8 bf = *(const bf16x8*)(lb + off);
        acc[nt] = __builtin_amdgcn_mfma_f32_16x16x32_bf16(af, bf, acc[nt], 0, 0, 0);
      }
    }
    __syncthreads();
    cur0 = nxt0; cur1 = nxt1; cur2 = nxt2; cur3 = nxt3;
  }

  // epilogue: C frag layout col = lane&15, row = (lane>>4)*4 + r
  float* po = part + ((size_t)ks * NROWS + (size_t)mtile * 128 + w * 16) * NDOUT;
  #pragma unroll
  for (int nt = 0; nt < 8; ++nt) {
    #pragma unroll
    for (int r = 0; r < 4; ++r) {
      po[(g * 4 + r) * NDOUT + nt * 16 + lm] = acc[nt][r];
    }
  }
}

// Sum NKS partials, write transposed bf16 FT[128][16384].
template<int NKS>
__global__ void reduce_ft(const float* __restrict__ part,
                          unsigned short* __restrict__ FT)
{
  const int t = blockIdx.x * 256 + threadIdx.x;   // 131072 threads
  const int n = t & 127;
  const int mg = t >> 7;                          // 0..1023, 16 m each
  const size_t base = (size_t)mg * 16 * NDOUT + n;
  unsigned r_[8];
  #pragma unroll
  for (int j = 0; j < 8; ++j) {
    float s0 = 0.f, s1 = 0.f;
    #pragma unroll
    for (int ksi = 0; ksi < NKS; ++ksi) {
      const float* p = part + (size_t)ksi * (NROWS * NDOUT) + base;
      s0 += p[(size_t)(2 * j) * NDOUT];
      s1 += p[(size_t)(2 * j + 1) * NDOUT];
    }
    r_[j] = (unsigned)f2bf(s0) | ((unsigned)f2bf(s1) << 16);
  }
  uint4* dst = (uint4*)(FT + (size_t)n * NROWS + mg * 16);
  dst[0] = make_uint4(r_[0], r_[1], r_[2], r_[3]);
  dst[1] = make_uint4(r_[4], r_[5], r_[6], r_[7]);
}

// Final: sum 4 partials, relu, fp32 out [16384][128]
__global__ void reduce_out(const float* __restrict__ part, float* __restrict__ out)
{
  const int t = blockIdx.x * 256 + threadIdx.x;   // 524288 threads x float4
  const float4* p = (const float4*)part;
  float4 s = p[t];
  #pragma unroll
  for (int ksi = 1; ksi < 4; ++ksi) {
    float4 q = p[(size_t)ksi * (NROWS * NDOUT / 4) + t];
    s.x += q.x; s.y += q.y; s.z += q.z; s.w += q.w;
  }
  s.x = fmaxf(s.x, 0.f); s.y = fmaxf(s.y, 0.f);
  s.z = fmaxf(s.z, 0.f); s.w = fmaxf(s.w, 0.f);
  ((float4*)out)[t] = s;
}

// W [512][128] f32 -> WT [128][512] bf16
__global__ void wconv(const float* __restrict__ W, unsigned short* __restrict__ WT)
{
  const int t = blockIdx.x * 256 + threadIdx.x;   // 65536
  const int n = t & 127, k = t >> 7;
  WT[(size_t)n * KDIN + k] = f2bf(W[(size_t)k * NDOUT + n]);
}

extern "C" void kernel_launch(void* const* d_in, const int* in_sizes, int n_in,
                              void* d_out, int out_size, void* d_ws, size_t ws_size,
                              hipStream_t stream)
{
  const float* x       = (const float*)d_in[0];
  const float* support = (const float*)d_in[1];
  const float* weight  = (const float*)d_in[2];
  const float* dmask   = (const float*)d_in[3];
  float* out = (float*)d_out;
  char* ws = (char*)d_ws;

  // ws layout: FTa 4MiB | FTb 4MiB | WT 128KiB (@8MiB) | part 32MiB (@9MiB) = 41MiB
  unsigned short* FTa = (unsigned short*)(ws);
  unsigned short* FTb = (unsigned short*)(ws + (size_t)(4 << 20));
  unsigned short* WT  = (unsigned short*)(ws + (size_t)(8 << 20));
  float* part         = (float*)(ws + (size_t)(9 << 20));

  // 1. W -> WT (transposed bf16)
  wconv<<<256, 256, 0, stream>>>(weight, WT);
  // 2. pre_sup = (x .* mask / 0.9) @ W   (K=512, K-split 2)
  gemm_stage<1, 2><<<256, 512, 0, stream>>>(x, dmask, WT, KDIN, KDIN, 256, part);
  reduce_ft<2><<<512, 256, 0, stream>>>(part, FTa);
  // 3. three diffusion steps: feat <- S @ feat   (K=16384, K-split 4)
  gemm_stage<0, 4><<<512, 512, 0, stream>>>(support, (const float*)0, FTa, NROWS, NROWS, 4096, part);
  reduce_ft<4><<<512, 256, 0, stream>>>(part, FTb);
  gemm_stage<0, 4><<<512, 512, 0, stream>>>(support, (const float*)0, FTb, NROWS, NROWS, 4096, part);
  reduce_ft<4><<<512, 256, 0, stream>>>(part, FTa);
  gemm_stage<0, 4><<<512, 512, 0, stream>>>(support, (const float*)0, FTa, NROWS, NROWS, 4096, part);
  // 4. sum + relu -> d_out fp32
  reduce_out<<<2048, 256, 0, stream>>>(part, out);
  (void)in_sizes; (void)n_in; (void)out_size; (void)ws_size;
}